// Round 4
// baseline (223.593 us; speedup 1.0000x reference)
//
#include <hip/hip_runtime.h>

// ---------------------------------------------------------------------------
// MultiHeadAttention (B=2, E=512, H=8, T=2048, DH=64), fp32 in/out.
//   K1 wstd:   weight-standardize Wq/Wk/Wv/Wo -> bf16; also key_mask -> fp32
//   K2 trans:  x[b][i][t]*mask[t] -> xT[src][b][t][i] bf16   (masks folded)
//   K3 proj:   Y = Wn @ xT^T + bias, per-head LN fused; XOR-swizzled LDS
//              Q -> bf16 [B][H][T][DH] scaled by log2e/181; K -> bf16; V -> f16 [B][H][DH][T]
//   K4 attn:   S^T register-softmax flash attention, q-tile 32 (1024 blocks,
//              4 blocks/CU). QK^T bf16 K=32 MFMA -> exp2 in regs -> PV f16
//              16x16x16 MFMA. No LDS in K-loop.
//   K5 oproj:  out = WnO @ xa^T + bo -> fp32; 64x64 tiles
// ---------------------------------------------------------------------------

typedef __bf16 bf16;
typedef __bf16 bf16x2 __attribute__((ext_vector_type(2)));
typedef __bf16 bf16x8 __attribute__((ext_vector_type(8)));
typedef _Float16 f16;
typedef _Float16 f16x4 __attribute__((ext_vector_type(4)));
typedef float  f32x4  __attribute__((ext_vector_type(4)));

#define MFMA_BF16(a, b, c) __builtin_amdgcn_mfma_f32_16x16x32_bf16((a), (b), (c), 0, 0, 0)
#define MFMA_F16_K16(a, b, c) __builtin_amdgcn_mfma_f32_16x16x16f16((a), (b), (c), 0, 0, 0)

#if __has_builtin(__builtin_amdgcn_exp2f)
#define EXP2F(x) __builtin_amdgcn_exp2f(x)
#else
#define EXP2F(x) __expf((x) * 0.6931471805599453f)
#endif

#define NB   2
#define NE   512
#define NH   8
#define NT   2048
#define NDH  64

__device__ __forceinline__ void gl_lds16(const bf16* g, bf16* l) {
  __builtin_amdgcn_global_load_lds(
      (const __attribute__((address_space(1))) void*)g,
      (__attribute__((address_space(3))) void*)l, 16, 0, 0);
}

// ---------------- K1: weight standardization + mask cast -------------------
__global__ __launch_bounds__(64) void k_wstd(
    const float* __restrict__ Wq, const float* __restrict__ Wk,
    const float* __restrict__ Wv, const float* __restrict__ Wo,
    const int* __restrict__ km,
    bf16* __restrict__ out, float* __restrict__ kmf)
{
  if (blockIdx.y == 4) {   // key_mask int -> float
    int idx = blockIdx.x * 64 + threadIdx.x;
    if (idx < NB * NT) kmf[idx] = (float)km[idx];
    return;
  }
  const float* W = blockIdx.y == 0 ? Wq : blockIdx.y == 1 ? Wk
                 : blockIdx.y == 2 ? Wv : Wo;
  int row = blockIdx.x, lane = threadIdx.x;
  const float4* p = (const float4*)(W + row * NE) + lane * 2;
  float4 a = p[0], c = p[1];
  float s  = a.x + a.y + a.z + a.w + c.x + c.y + c.z + c.w;
  float ss = a.x*a.x + a.y*a.y + a.z*a.z + a.w*a.w
           + c.x*c.x + c.y*c.y + c.z*c.z + c.w*c.w;
#pragma unroll
  for (int m = 1; m < 64; m <<= 1) { s += __shfl_xor(s, m); ss += __shfl_xor(ss, m); }
  float mean = s * (1.0f / NE);
  float var  = ss * (1.0f / NE) - mean * mean;
  float rstd = rsqrtf(var + 1e-5f);
  bf16x8 o;
  o[0] = (bf16)((a.x - mean) * rstd); o[1] = (bf16)((a.y - mean) * rstd);
  o[2] = (bf16)((a.z - mean) * rstd); o[3] = (bf16)((a.w - mean) * rstd);
  o[4] = (bf16)((c.x - mean) * rstd); o[5] = (bf16)((c.y - mean) * rstd);
  o[6] = (bf16)((c.z - mean) * rstd); o[7] = (bf16)((c.w - mean) * rstd);
  *(bf16x8*)(out + blockIdx.y * (NE * NE) + row * NE + lane * 8) = o;
}

// ---------------- K2: transpose + mask + cast ------------------------------
__global__ __launch_bounds__(256) void k_trans(
    const float* __restrict__ q, const float* __restrict__ k,
    const float* __restrict__ v,
    const int* __restrict__ qm, const int* __restrict__ km,
    const int* __restrict__ vm,
    bf16* __restrict__ xT)
{
  int src = blockIdx.z >> 1, b = blockIdx.z & 1;
  const float* x = src == 0 ? q : src == 1 ? k : v;
  const int*   m = src == 0 ? qm : src == 1 ? km : vm;
  x += (size_t)b * NE * NT;
  m += b * NT;
  int t0 = blockIdx.x * 64, i0 = blockIdx.y * 64;
  __shared__ float tile[64][65];
  int lr = threadIdx.x >> 4;            // row-in-pass 0..15
  int tc = (threadIdx.x & 15) * 4;      // t offset, float4
#pragma unroll
  for (int p = 0; p < 4; p++) {
    int row = p * 16 + lr;
    float4 v4 = *(const float4*)(x + (size_t)(i0 + row) * NT + t0 + tc);
    tile[row][tc]     = v4.x; tile[row][tc + 1] = v4.y;
    tile[row][tc + 2] = v4.z; tile[row][tc + 3] = v4.w;
  }
  __syncthreads();
  bf16* o = xT + ((size_t)src * NB + b) * NT * NE;
  int i2 = (threadIdx.x & 31) * 2, t2 = threadIdx.x >> 5;  // 8 t per pass
#pragma unroll
  for (int t = t2; t < 64; t += 8) {
    float mk = (float)m[t0 + t];
    bf16x2 w2;
    w2[0] = (bf16)(tile[i2][t] * mk);
    w2[1] = (bf16)(tile[i2 + 1][t] * mk);
    *(bf16x2*)(o + (size_t)(t0 + t) * NE + i0 + i2) = w2;
  }
}

// ---------------- K3: projection GEMM + fused per-head LN ------------------
__global__ __launch_bounds__(256) void k_proj(
    const bf16* __restrict__ Wn,   // [3+1][512][512]
    const bf16* __restrict__ xT,   // [3][B][T][E]
    const float* __restrict__ bq, const float* __restrict__ bk,
    const float* __restrict__ bv,
    const float* __restrict__ gq, const float* __restrict__ bbq,
    const float* __restrict__ gk, const float* __restrict__ bbk,
    const float* __restrict__ gv, const float* __restrict__ bbv,
    bf16* __restrict__ Qh, bf16* __restrict__ Kh, f16* __restrict__ Vh)
{
  int src = blockIdx.z >> 1, b = blockIdx.z & 1;
  const bf16* A  = Wn + src * (NE * NE);
  const bf16* Bm = xT + ((size_t)src * NB + b) * NT * NE;
  int m0 = blockIdx.y * 64, n0 = blockIdx.x * 128;
  int h = m0 >> 6;

  __shared__ __align__(16) char smem[64 * 130 * 4 + 2 * 128 * 4]; // 34304 B
  bf16*  Al = (bf16*)smem;            // [64][64] swizzled
  bf16*  Bl = (bf16*)(smem + 8192);   // [128][64] swizzled
  float* Yl = (float*)smem;           // [64][130]
  float* mu = (float*)(smem + 64 * 130 * 4);
  float* rs = mu + 128;

  int tid = threadIdx.x, lane = tid & 63, w = tid >> 6;
  int mh = (w & 1) * 32, nh = (w >> 1) * 64;
  f32x4 acc[2][4] = {};

  for (int k0 = 0; k0 < NE; k0 += 64) {
    __syncthreads();
#pragma unroll
    for (int i = 0; i < 2; i++) {
      int row = (w << 4) + (i << 3) + (lane >> 3);
      int chg = (lane & 7) ^ (row & 7);
      gl_lds16(A + (m0 + row) * NE + k0 + (chg << 3),
               Al + ((w << 4) + (i << 3)) * 64);
    }
#pragma unroll
    for (int i = 0; i < 4; i++) {
      int row = (w << 5) + (i << 3) + (lane >> 3);
      int chg = (lane & 7) ^ (row & 7);
      gl_lds16(Bm + (size_t)(n0 + row) * NE + k0 + (chg << 3),
               Bl + ((w << 5) + (i << 3)) * 64);
    }
    __syncthreads();
#pragma unroll
    for (int kk = 0; kk < 64; kk += 32) {
      bf16x8 af[2], bfv[4];
#pragma unroll
      for (int ms = 0; ms < 2; ms++) {
        int row = mh + ms * 16 + (lane & 15);
        af[ms] = *(const bf16x8*)(Al + row * 64 +
                   ((((kk >> 3) + (lane >> 4)) ^ (row & 7)) << 3));
      }
#pragma unroll
      for (int ns = 0; ns < 4; ns++) {
        int row = nh + ns * 16 + (lane & 15);
        bfv[ns] = *(const bf16x8*)(Bl + row * 64 +
                   ((((kk >> 3) + (lane >> 4)) ^ (row & 7)) << 3));
      }
#pragma unroll
      for (int ms = 0; ms < 2; ms++)
#pragma unroll
        for (int ns = 0; ns < 4; ns++)
          acc[ms][ns] = MFMA_BF16(af[ms], bfv[ns], acc[ms][ns]);
    }
  }

  __syncthreads();
  {
    const float* bias = src == 0 ? bq : src == 1 ? bk : bv;
#pragma unroll
    for (int ms = 0; ms < 2; ms++)
#pragma unroll
      for (int ns = 0; ns < 4; ns++)
#pragma unroll
        for (int r = 0; r < 4; r++) {
          int om = mh + ms * 16 + ((lane >> 4) << 2) + r;
          int on = nh + ns * 16 + (lane & 15);
          Yl[om * 130 + on] = acc[ms][ns][r] + bias[m0 + om];
        }
  }
  __syncthreads();
  if (tid < 128) {
    float s = 0.f, ss = 0.f;
#pragma unroll 8
    for (int o = 0; o < 64; o++) { float y = Yl[o * 130 + tid]; s += y; ss += y * y; }
    float mean = s * (1.0f / 64.0f);
    float var  = ss * (1.0f / 64.0f) - mean * mean;
    mu[tid] = mean;
    rs[tid] = rsqrtf(var + 1e-5f);
  }
  __syncthreads();

  if (src < 2) {
    // Q: fold softmax scale AND log2(e) so attn uses raw v_exp_f32 (exp2).
    float scl = (src == 0) ? (1.4426950408889634f / 181.0f) : 1.0f;
    const float* g  = src == 0 ? gq  : gk;
    const float* bb = src == 0 ? bbq : bbk;
    bf16* out = (src == 0 ? Qh : Kh) + ((size_t)(b * NH + h) * NT + n0) * NDH;
    int d = tid & 63, tb = tid >> 6;
    float gg = g[d] * scl, bb2 = bb[d] * scl;
#pragma unroll
    for (int t = tb; t < 128; t += 4) {
      float val = (Yl[d * 130 + t] - mu[t]) * rs[t] * gg + bb2;
      out[(size_t)t * NDH + d] = (bf16)val;
    }
  } else {
    f16* out = Vh + (size_t)(b * NH + h) * NDH * NT + n0;
    int t = tid & 127, db = tid >> 7;
#pragma unroll
    for (int d = db; d < 64; d += 2) {
      float val = (Yl[d * 130 + t] - mu[t]) * rs[t] * gv[d] + bbv[d];
      out[(size_t)d * NT + t] = (f16)val;
    }
  }
}

// ---------------- K4: flash attention v4 (q-tile 32, 1024 blocks) ----------
// grid (T/32, B*H), block 256 = 4 waves; wave w owns keys [w*32, w*32+32)
// of each 128-key tile, all 32 q. S^T = K·Q^T (bf16 K=32); C-layout of S^T
// (q=lane&15, key=quad*4+r) IS the A-layout of f16 K=16 MFMA -> exp2 stays
// in registers; PV via 16x16x16f16. No LDS in K-loop.
__global__ __launch_bounds__(256, 4) void k_attn(
    const bf16* __restrict__ Qh, const bf16* __restrict__ Kh,
    const f16* __restrict__ Vh,
    const float* __restrict__ kmf, const int* __restrict__ qmask,
    bf16* __restrict__ xa)  // [B][T][E]
{
  int bh = blockIdx.y, b = bh >> 3, h = bh & 7;
  int q0 = blockIdx.x * 32;
  const bf16* Q = Qh + (size_t)bh * NT * NDH;
  const bf16* K = Kh + (size_t)bh * NT * NDH;
  const f16*  V = Vh + (size_t)bh * NDH * NT;

  __shared__ __align__(16) char smem[2 * 32 * 68 * 4 + 4 * 32 * 4]; // 17920 B
  float* OlA  = (float*)smem;                     // [32][68]
  float* OlB  = (float*)(smem + 32 * 68 * 4);     // [32][68]
  float* denl = (float*)(smem + 2 * 32 * 68 * 4); // [4][32]

  int tid = threadIdx.x, lane = tid & 63, w = tid >> 6;
  int quad = lane >> 4, l15 = lane & 15;
  const int ko = w * 32;

  // Q as B-operand: n=q=lane&15, k(d)=quad*8+j
  bf16x8 qb[2][2];
#pragma unroll
  for (int qs = 0; qs < 2; qs++)
#pragma unroll
    for (int hf = 0; hf < 2; hf++)
      qb[qs][hf] = *(const bf16x8*)(Q + (size_t)(q0 + qs * 16 + l15) * NDH + hf * 32 + quad * 8);

  const bf16*  Kb = K + (size_t)(ko + l15) * NDH + quad * 8;
  const f16*   Vb = V + (size_t)l15 * NT + ko + quad * 4;
  const float* Mb = kmf + b * NT + ko + quad * 4;

  f32x4 acco[2][4] = {};   // [qs][ds]
  float den[2] = {};       // per-lane partial den for q = qs*16 + l15

  bf16x8 ka[2][2];   // [kt][hf]: A-operand of QK^T (m=key)
  f16x4  vb[4][2];   // [ds][kt]: B-operand of PV (n=d, k=key)
#pragma unroll
  for (int kt = 0; kt < 2; kt++)
#pragma unroll
    for (int hf = 0; hf < 2; hf++)
      ka[kt][hf] = *(const bf16x8*)(Kb + (size_t)(kt * 16) * NDH + hf * 32);
#pragma unroll
  for (int ds = 0; ds < 4; ds++)
#pragma unroll
    for (int kt = 0; kt < 2; kt++)
      vb[ds][kt] = *(const f16x4*)(Vb + (size_t)(ds * 16) * NT + kt * 16);

  for (int k0 = 0; k0 < NT; k0 += 128) {
    int k1 = (k0 + 128) & (NT - 1);   // wrap: last-iter prefetch unused
    bf16x8 nka[2][2];
    f16x4  nvb[4][2];
#pragma unroll
    for (int kt = 0; kt < 2; kt++)
#pragma unroll
      for (int hf = 0; hf < 2; hf++)
        nka[kt][hf] = *(const bf16x8*)(Kb + (size_t)(k1 + kt * 16) * NDH + hf * 32);
#pragma unroll
    for (int ds = 0; ds < 4; ds++)
#pragma unroll
      for (int kt = 0; kt < 2; kt++)
        nvb[ds][kt] = *(const f16x4*)(Vb + (size_t)(ds * 16) * NT + k1 + kt * 16);

    float4 kmv0 = *(const float4*)(Mb + k0);
    float4 kmv1 = *(const float4*)(Mb + k0 + 16);

#pragma unroll
    for (int kt = 0; kt < 2; kt++) {
      const float4 kmv = kt ? kmv1 : kmv0;
      f32x4 s[2];
#pragma unroll
      for (int qs = 0; qs < 2; qs++) {
        f32x4 z = {};
        z = MFMA_BF16(ka[kt][0], qb[qs][0], z);
        z = MFMA_BF16(ka[kt][1], qb[qs][1], z);
        s[qs] = z;
      }
      f16x4 pa[2];
#pragma unroll
      for (int qs = 0; qs < 2; qs++) {
        float p0 = EXP2F(s[qs][0]) * kmv.x;
        float p1 = EXP2F(s[qs][1]) * kmv.y;
        float p2 = EXP2F(s[qs][2]) * kmv.z;
        float p3 = EXP2F(s[qs][3]) * kmv.w;
        den[qs] += (p0 + p1) + (p2 + p3);
        f16x4 pv; pv[0] = (f16)p0; pv[1] = (f16)p1; pv[2] = (f16)p2; pv[3] = (f16)p3;
        pa[qs] = pv;
      }
#pragma unroll
      for (int qs = 0; qs < 2; qs++)
#pragma unroll
        for (int ds = 0; ds < 4; ds++)
          acco[qs][ds] = MFMA_F16_K16(pa[qs], vb[ds][kt], acco[qs][ds]);
    }

#pragma unroll
    for (int kt = 0; kt < 2; kt++)
#pragma unroll
      for (int hf = 0; hf < 2; hf++)
        ka[kt][hf] = nka[kt][hf];
#pragma unroll
    for (int ds = 0; ds < 4; ds++)
#pragma unroll
      for (int kt = 0; kt < 2; kt++)
        vb[ds][kt] = nvb[ds][kt];
  }

  // reduce den across the 4 quads
#pragma unroll
  for (int qs = 0; qs < 2; qs++) {
    den[qs] += __shfl_xor(den[qs], 16);
    den[qs] += __shfl_xor(den[qs], 32);
  }
  if (quad == 0)
#pragma unroll
    for (int qs = 0; qs < 2; qs++)
      denl[w * 32 + qs * 16 + l15] = den[qs];

  // cross-wave O combine: waves {0,1}->OlA, {2,3}->OlB
  float* Obuf = (w < 2) ? OlA : OlB;
  if ((w & 1) == 0) {
#pragma unroll
    for (int qs = 0; qs < 2; qs++)
#pragma unroll
      for (int ds = 0; ds < 4; ds++)
#pragma unroll
        for (int r = 0; r < 4; r++)
          Obuf[(qs * 16 + quad * 4 + r) * 68 + ds * 16 + l15] = acco[qs][ds][r];
  }
  __syncthreads();
  if (w & 1) {
#pragma unroll
    for (int qs = 0; qs < 2; qs++)
#pragma unroll
      for (int ds = 0; ds < 4; ds++)
#pragma unroll
        for (int r = 0; r < 4; r++)
          Obuf[(qs * 16 + quad * 4 + r) * 68 + ds * 16 + l15] += acco[qs][ds][r];
  }
  __syncthreads();

#pragma unroll
  for (int i = 0; i < 8; i++) {
    int ql = w * 8 + i;
    float dtot = denl[ql] + denl[32 + ql] + denl[64 + ql] + denl[96 + ql];
    float qm = (float)qmask[b * NT + q0 + ql];
    float inv = qm / dtot;   // masked query -> exact 0
    float val = (OlA[ql * 68 + lane] + OlB[ql * 68 + lane]) * inv;
    xa[((size_t)b * NT + q0 + ql) * NE + h * NDH + lane] = (bf16)val;
  }
}

// ---------------- K5: output projection (64x64 tiles, 512 blocks) ----------
__global__ __launch_bounds__(256) void k_oproj(
    const bf16* __restrict__ A,    // WnO [512][512]
    const bf16* __restrict__ xab,  // [B][T][E]
    const float* __restrict__ bo, float* __restrict__ out)
{
  int b = blockIdx.z;
  const bf16* Bm = xab + (size_t)b * NT * NE;
  int m0 = blockIdx.y * 64, n0 = blockIdx.x * 64;

  __shared__ __align__(16) char smem[16384];
  bf16* Al = (bf16*)smem;           // [64][64] swizzled
  bf16* Bl = (bf16*)(smem + 8192);  // [64][64] swizzled

  int tid = threadIdx.x, lane = tid & 63, w = tid >> 6;
  int mh = (w & 1) * 32, nh = (w >> 1) * 32;
  f32x4 acc[2][2] = {};

  for (int k0 = 0; k0 < NE; k0 += 64) {
    __syncthreads();
#pragma unroll
    for (int i = 0; i < 2; i++) {
      int row = (w << 4) + (i << 3) + (lane >> 3);
      int chg = (lane & 7) ^ (row & 7);
      gl_lds16(A + (m0 + row) * NE + k0 + (chg << 3),
               Al + ((w << 4) + (i << 3)) * 64);
    }
#pragma unroll
    for (int i = 0; i < 2; i++) {
      int row = (w << 4) + (i << 3) + (lane >> 3);
      int chg = (lane & 7) ^ (row & 7);
      gl_lds16(Bm + (size_t)(n0 + row) * NE + k0 + (chg << 3),
               Bl + ((w << 4) + (i << 3)) * 64);
    }
    __syncthreads();
#pragma unroll
    for (int kk = 0; kk < 64; kk += 32) {
      bf16x8 af[2], bfv[2];
#pragma unroll
      for (int ms = 0; ms < 2; ms++) {
        int row = mh + ms * 16 + (lane & 15);
        af[ms] = *(const bf16x8*)(Al + row * 64 +
                   ((((kk >> 3) + (lane >> 4)) ^ (row & 7)) << 3));
      }
#pragma unroll
      for (int ns = 0; ns < 2; ns++) {
        int row = nh + ns * 16 + (lane & 15);
        bfv[ns] = *(const bf16x8*)(Bl + row * 64 +
                   ((((kk >> 3) + (lane >> 4)) ^ (row & 7)) << 3));
      }
#pragma unroll
      for (int ms = 0; ms < 2; ms++)
#pragma unroll
        for (int ns = 0; ns < 2; ns++)
          acc[ms][ns] = MFMA_BF16(af[ms], bfv[ns], acc[ms][ns]);
    }
  }

#pragma unroll
  for (int ms = 0; ms < 2; ms++)
#pragma unroll
    for (int ns = 0; ns < 2; ns++)
#pragma unroll
      for (int r = 0; r < 4; r++) {
        int o = m0 + mh + ms * 16 + ((lane >> 4) << 2) + r;
        int t = n0 + nh + ns * 16 + (lane & 15);
        out[(size_t)b * NE * NT + (size_t)o * NT + t] = acc[ms][ns][r] + bo[o];
      }
}

// ---------------------------------------------------------------------------
extern "C" void kernel_launch(void* const* d_in, const int* in_sizes, int n_in,
                              void* d_out, int out_size, void* d_ws, size_t ws_size,
                              hipStream_t stream)
{
  const float* q  = (const float*)d_in[0];
  const float* k  = (const float*)d_in[1];
  const float* v  = (const float*)d_in[2];
  const int*   qm = (const int*)d_in[3];
  const int*   km = (const int*)d_in[4];
  const int*   vm = (const int*)d_in[5];
  const float* Wq = (const float*)d_in[6];  const float* bq = (const float*)d_in[7];
  const float* Wk = (const float*)d_in[8];  const float* bk = (const float*)d_in[9];
  const float* Wv = (const float*)d_in[10]; const float* bv = (const float*)d_in[11];
  const float* Wo = (const float*)d_in[12]; const float* bo = (const float*)d_in[13];
  const float* gq = (const float*)d_in[14]; const float* bbq = (const float*)d_in[15];
  const float* gk = (const float*)d_in[16]; const float* bbk = (const float*)d_in[17];
  const float* gv = (const float*)d_in[18]; const float* bbv = (const float*)d_in[19];
  float* out = (float*)d_out;

  char* wsb = (char*)d_ws;
  bf16*  Wn  = (bf16*)(wsb);                        //  2 MiB: 4x[512][512]
  bf16*  xT  = (bf16*)(wsb + (2ull  << 20));        // 12 MiB: 3x[B][T][E]
  bf16*  Qh  = (bf16*)(wsb + (14ull << 20));        //  4 MiB: [B][H][T][DH]
  bf16*  Kh  = (bf16*)(wsb + (18ull << 20));        //  4 MiB
  f16*   Vh  = (f16*) (wsb + (22ull << 20));        //  4 MiB: [B][H][DH][T] f16
  bf16*  xa  = (bf16*)(wsb + (26ull << 20));        //  4 MiB: [B][T][E]
  float* kmf = (float*)(wsb + (30ull << 20));       // 16 KiB: [B][T]

  k_wstd <<<dim3(512, 5),   64,  0, stream>>>(Wq, Wk, Wv, Wo, km, Wn, kmf);
  k_trans<<<dim3(32, 8, 6), 256, 0, stream>>>(q, k, v, qm, km, vm, xT);
  k_proj <<<dim3(16, 8, 6), 256, 0, stream>>>(Wn, xT, bq, bk, bv,
                                              gq, bbq, gk, bbk, gv, bbv,
                                              Qh, Kh, Vh);
  k_attn <<<dim3(64, 16),   256, 0, stream>>>(Qh, Kh, Vh, kmf, qm, xa);
  k_oproj<<<dim3(32, 8, 2), 256, 0, stream>>>(Wn + 3 * NE * NE, xa, bo, out);
}